// Round 10
// baseline (396.076 us; speedup 1.0000x reference)
//
#include <hip/hip_runtime.h>

// VarianceAdaptor: B=16, S=512, C(D_MODEL)=F(FILTER)=512, K=3, T(MAX_FRAMES)=2048
#define B_ 16
#define S_ 512
#define C_ 512
#define T_ 2048

typedef __attribute__((ext_vector_type(8))) short short8;
typedef __attribute__((ext_vector_type(4))) float floatx4;

__device__ __forceinline__ unsigned short f2bf(float x) {
    union { float f; unsigned u; } c; c.f = x;
    unsigned r = (c.u + 0x7fffu + ((c.u >> 16) & 1u)) >> 16;
    return (unsigned short)r;
}

// async global->LDS, 16B per lane; lds dest = wave-uniform base + lane*16
__device__ __forceinline__ void gld_lds16(void* l, const void* g) {
    __builtin_amdgcn_global_load_lds(
        (const __attribute__((address_space(1))) void*)g,
        (__attribute__((address_space(3))) void*)l, 16, 0, 0);
}

// ---------------------------------------------------------------------------
// Fused prep (unchanged): pack 6 conv weights (F,C,3)fp32 -> (3,F,C)bf16,
// cast H->bf16, zero zrow, length-regulator rowidx, fill preds w/ final bias.
__global__ void prep_kernel(const float* __restrict__ w0, const float* __restrict__ w1,
                            const float* __restrict__ w2, const float* __restrict__ w3,
                            const float* __restrict__ w4, const float* __restrict__ w5,
                            unsigned short* __restrict__ wpack,
                            const float* __restrict__ H, unsigned short* __restrict__ Hbf,
                            unsigned short* __restrict__ zrow,
                            const int* __restrict__ Dgt, int* __restrict__ ridx,
                            float* __restrict__ Dp, float* __restrict__ Pp, float* __restrict__ Ep,
                            const float* __restrict__ dbl, const float* __restrict__ pbl,
                            const float* __restrict__ ebl) {
    __shared__ int cs[S_];
    __shared__ int ps[256];
    int blk = blockIdx.x;
    int tid = threadIdx.x;
    if (blk < 6144) {                      // weight pack: 6 x 1024 blocks
        int which = blk >> 10;
        const float* w = which == 0 ? w0 : which == 1 ? w1 : which == 2 ? w2
                       : which == 3 ? w3 : which == 4 ? w4 : w5;
        unsigned short* wp = wpack + (long)which * 786432;
        int i = (blk & 1023) * 256 + tid;   // i over F*C = 262144
        const float* s = w + (long)i * 3;
        wp[i]          = f2bf(s[0]);
        wp[i + 262144] = f2bf(s[1]);
        wp[i + 524288] = f2bf(s[2]);
    } else if (blk < 10240) {              // H fp32 -> bf16: 4096 blocks x 4 elems
        int i = (blk - 6144) * 256 + tid;
        float4 v = *(const float4*)(H + (long)i * 4);
        ushort4 o;
        o.x = f2bf(v.x); o.y = f2bf(v.y); o.z = f2bf(v.z); o.w = f2bf(v.w);
        *(ushort4*)(Hbf + (long)i * 4) = o;
    } else if (blk < 10242) {              // zrow: 2 blocks
        zrow[(blk - 10240) * 256 + tid] = 0;
    } else if (blk < 10258) {              // expand rowidx: 16 blocks (one/batch)
        int b = blk - 10242;
        int t2 = tid * 2;
        int d0 = Dgt[b * S_ + t2], d1 = Dgt[b * S_ + t2 + 1];
        int a0 = d0 < 0 ? 0 : d0, a1 = d1 < 0 ? 0 : d1;
        ps[tid] = a0 + a1;
        __syncthreads();
        for (int off = 1; off < 256; off <<= 1) {
            int v = (tid >= off) ? ps[tid - off] : 0;
            __syncthreads();
            ps[tid] += v;
            __syncthreads();
        }
        int incl = ps[tid];
        cs[t2] = incl - a1;
        cs[t2 + 1] = incl;
        __syncthreads();
        int total = cs[S_ - 1];
        int limit = total < T_ ? total : T_;
        for (int t = tid; t < T_; t += 256) {
            int lo = 0, hi = S_;
            while (lo < hi) { int mid = (lo + hi) >> 1; if (cs[mid] <= t) lo = mid + 1; else hi = mid; }
            if (lo > S_ - 1) lo = S_ - 1;
            ridx[b * T_ + t] = (t < limit) ? lo : -1;
        }
    } else {                               // fill preds: 288 blocks
        int i = (blk - 10258) * 256 + tid;
        if (i < 8192) Dp[i] = dbl[0];
        else if (i < 40960) Pp[i - 8192] = pbl[0];
        else Ep[i - 40960] = ebl[0];
    }
}

// ---------------------------------------------------------------------------
// 128(f) x 512(p) tile, 8 waves (2m x 4n), wave = 64x128, acc[4][8], BK=32.
//   D[f, p] = sum_{tap, c} W[tap][f][c] * X[row(p + tap - 1)][c]
// One sync pair per c-block: all 3 taps' W (6 slots, parity-double-buffered)
// + X (2 buffers, 514 rows) resident simultaneously -> per cc:
//   VMWAIT(0) + barrier ; stage cc+1 into opposite parity ; 3 taps of
//   {12 ds_read_b128 + 32 MFMA} straight-line (compiler-scheduled).
// 16 barriers/block (vs 48 in R7), every wait vmcnt(0) with >= 3-phase
// prefetch slack (covers HBM latency; also removes R7's latent vmcnt(5)
// race where waves 1-7 only had the oldest of 6 outstanding loads
// guaranteed).  LDS = 6x8KB W + 2x32.9KB X = 112.2 KB -> 1 block/CU,
// 8 waves.  Swizzle (R2/R6/R7-verified, 0 conflicts): rows of 32 shorts
// (4 x 16B chunks); chunk c8 of row r holds global chunk c8 ^ ((r>>1)&3);
// linear LDS dest for global_load_lds, inverse-swizzled global source.
// R9 fix: edge-row source index was 512+(tid>>3) (always row 512) -> row 513
// got row 512's data; correct is 512+(tid>>2) (chunks 0-3 -> 512, 4-7 -> 513).
struct ConvJob {
    const unsigned short* X;    // bf16 rows [B << Bshift][C]
    const int* ridx;            // per (b,t) row-in-batch, or nullptr = identity
    int Lshift;                 // log2 positions per batch
    int Bshift;                 // log2 rows per batch of X
    const unsigned short* wp;   // [3][512][512] bf16
    const float* bias;
    const float* wl;
    void* dst;
    int nxshift;                // log2 of position tiles (BN=512)
};

template <int TAP>
__device__ __forceinline__ void compute_kt(
    floatx4 (&acc)[4][8],
    const unsigned short* Wb, const unsigned short* Xb,
    int wm, int wn, int q, int lr)
{
    // B (X) frags: row wn*128 + jj*16 + lr + TAP; stored chunk q^((row>>1)&3)
    short8 bfr[8];
    const int sX = ((lr + TAP) >> 1) & 3;
#pragma unroll
    for (int jj = 0; jj < 8; ++jj) {
        const int xr = wn * 128 + jj * 16 + lr + TAP;
        bfr[jj] = *(const short8*)(Xb + xr * 32 + ((q ^ sX) * 8));
    }
    const int sA = (lr >> 1) & 3;
#pragma unroll
    for (int i = 0; i < 4; ++i) {
        const int rA = wm * 64 + i * 16 + lr;
        short8 a = *(const short8*)(Wb + rA * 32 + ((q ^ sA) * 8));
#pragma unroll
        for (int jj = 0; jj < 8; ++jj)
            acc[i][jj] = __builtin_amdgcn_mfma_f32_16x16x32_bf16(a, bfr[jj], acc[i][jj], 0, 0, 0);
    }
}

// counted wait + publish barrier at c-block start
#define VMWAIT(n) do { \
    asm volatile("s_waitcnt vmcnt(" #n ")" ::: "memory"); \
    __builtin_amdgcn_sched_barrier(0); \
    __builtin_amdgcn_s_barrier(); \
    __builtin_amdgcn_sched_barrier(0); \
} while (0)

__global__ __launch_bounds__(512, 2) void mega_kernel(
    ConvJob j0, ConvJob j1, ConvJob j2, int e0, int e1, int e2, int mode, int aoff,
    const unsigned short* __restrict__ zrow,
    const float* __restrict__ H, const int* __restrict__ aridx,
    const float* __restrict__ Pgt, const float* __restrict__ Egt,
    const float* __restrict__ pw, const float* __restrict__ pb,
    const float* __restrict__ ew, const float* __restrict__ eb,
    float* __restrict__ aout)
{
    extern __shared__ unsigned short lds[];   // 114944 B: W[2][3][4096] + X[2][16448] shorts
    const int bx = blockIdx.x;
    const int tid = threadIdx.x;

    if (bx >= e2) {
        // ---- adapt path: 512-thread blocks, aoff selects half ----
        int ab = bx - e2 + aoff;
#pragma unroll
        for (int it = 0; it < 8; ++it) {
            int i = ab * 512 + tid + it * 524288;
            int f4 = i & 127;
            int p  = i >> 7;
            int b  = p >> 11;
            int r  = aridx[p];
            float pg = Pgt[p], eg = Egt[p];
            int f = f4 << 2;
            float4 pwv = *(const float4*)(pw + f);
            float4 pbv = *(const float4*)(pb + f);
            float4 ewv = *(const float4*)(ew + f);
            float4 ebv = *(const float4*)(eb + f);
            float4 h = make_float4(0.f, 0.f, 0.f, 0.f);
            if (r >= 0) h = *(const float4*)(H + ((long)b * S_ + r) * C_ + f);
            float4 o;
            o.x = h.x + pg * pwv.x + pbv.x + eg * ewv.x + ebv.x;
            o.y = h.y + pg * pwv.y + pbv.y + eg * ewv.y + ebv.y;
            o.z = h.z + pg * pwv.z + pbv.z + eg * ewv.z + ebv.z;
            o.w = h.w + pg * pwv.w + pbv.w + eg * ewv.w + ebv.w;
            *(float4*)(aout + (long)p * C_ + f) = o;
        }
        return;
    }

    ConvJob j;
    int local;
    if (bx < e0)      { j = j0; local = bx; }
    else if (bx < e1) { j = j1; local = bx - e0; }
    else              { j = j2; local = bx - e1; }
    const int m0 = (local >> j.nxshift) * 128;              // f tile (BM=128)
    const int n0 = (local & ((1 << j.nxshift) - 1)) * 512;  // p tile (BN=512)
    const int L = 1 << j.Lshift;
    const int b = n0 >> j.Lshift;
    const int t0 = n0 & (L - 1);

    unsigned short* WtS = lds;            // [2][3][4096]  (par, tap, 128 rows x 32)
    unsigned short* XtS = lds + 24576;    // [2][16448]    (par, 514 rows x 32)
    char* WtB = (char*)WtS;
    char* XtB = (char*)XtS;

    const int w = tid >> 6, l = tid & 63;
    const int q = l >> 4, lr = l & 15;
    const int wm = w & 1, wn = w >> 1;    // wave grid 2(m) x 4(n)

    floatx4 acc[4][8];
#pragma unroll
    for (int i = 0; i < 4; ++i)
#pragma unroll
        for (int jj = 0; jj < 8; ++jj) acc[i][jj] = (floatx4){0.f, 0.f, 0.f, 0.f};

    // ---- staging sources (16B chunks; inverse-swizzled source column) ----
    // chunk ch = qq*512 + tid: row = qq*128 + (tid>>2), c8 = tid&3;
    // source col-chunk = c8 ^ ((row>>1)&3) = (tid&3) ^ ((tid>>3)&3).
    const int sw = (((tid & 3) ^ ((tid >> 3) & 3))) * 8;
    auto xrowp = [&](int r) -> const unsigned short* {
        int t = t0 - 1 + r;
        if (t < 0 || t >= L) return zrow;
        int rr = j.ridx ? j.ridx[(b << j.Lshift) + t] : t;
        if (rr < 0) return zrow;
        return j.X + ((long)(b << j.Bshift) + rr) * C_;
    };
    const unsigned short* wsrcT[3];
#pragma unroll
    for (int tap = 0; tap < 3; ++tap)
        wsrcT[tap] = j.wp + (long)tap * 262144 + (long)(m0 + (tid >> 2)) * C_ + sw;
    const unsigned short* xsrc[4];
#pragma unroll
    for (int qq = 0; qq < 4; ++qq)
        xsrc[qq] = xrowp(qq * 128 + (tid >> 2)) + sw;
    // edge X rows 512,513: lanes 0-7 stage chunks 0-7 (row = 512 + (tid>>2),
    // col chunk = tid&3); (row>>1)&3 == 0 -> unswizzled source
    const unsigned short* xsrcE = xrowp(512 + (tid >> 2)) + (tid & 3) * 8;

    auto issueW = [&](int par, int tap, int koff) {     // 1 instr, 8 KB
        gld_lds16(WtB + (par * 3 + tap) * 8192 + w * 1024, wsrcT[tap] + koff);
    };
    auto issueX = [&](int par, int xoff) {              // 4-5 instrs, 32.9 KB
        gld_lds16(XtB + par * 32896 + 0 * 8192 + w * 1024, xsrc[0] + xoff);
        gld_lds16(XtB + par * 32896 + 1 * 8192 + w * 1024, xsrc[1] + xoff);
        gld_lds16(XtB + par * 32896 + 2 * 8192 + w * 1024, xsrc[2] + xoff);
        gld_lds16(XtB + par * 32896 + 3 * 8192 + w * 1024, xsrc[3] + xoff);
        if (tid < 8)
            gld_lds16(XtB + par * 32896 + 32768, xsrcE + xoff);
    };

    // ---- prologue: full cc=0 set -> parity 0 ----
    issueX(0, 0);
    issueW(0, 0, 0); issueW(0, 1, 0); issueW(0, 2, 0);

    // ---- main loop: one vmcnt(0)+barrier per cc; stage cc+1 into parity^1;
    // then 3 taps straight-line.  All waits drain fully (race-free); slack for
    // every load >= 3 tap-phases (~1900 cy) > HBM latency.
#pragma unroll 1
    for (int cc = 0; cc < 16; ++cc) {
        const int par = cc & 1;
        VMWAIT(0);
        if (cc < 15) {
            const int np = par ^ 1;
            const int ko = (cc + 1) * 32;
            issueW(np, 0, ko); issueW(np, 1, ko); issueW(np, 2, ko);
            issueX(np, ko);
        }
        const unsigned short* Wp = WtS + par * 12288;
        const unsigned short* Xb = XtS + par * 16448;
        compute_kt<0>(acc, Wp,        Xb, wm, wn, q, lr);
        compute_kt<1>(acc, Wp + 4096, Xb, wm, wn, q, lr);
        compute_kt<2>(acc, Wp + 8192, Xb, wm, wn, q, lr);
    }

    // ---- epilogue: D col = lane&15 = p, row = q*4 + reg = f ----
    const int fbase = m0 + wm * 64 + q * 4;
    const int pbase = n0 + wn * 128 + lr;
    if (mode == 0) {
        unsigned short* dst = (unsigned short*)j.dst;
#pragma unroll
        for (int i = 0; i < 4; ++i) {
            int f = fbase + i * 16;
            float4 bv = *(const float4*)(j.bias + f);
#pragma unroll
            for (int jj = 0; jj < 8; ++jj) {
                int p = pbase + jj * 16;
                ushort4 o;
                o.x = f2bf(fmaxf(acc[i][jj][0] + bv.x, 0.f));
                o.y = f2bf(fmaxf(acc[i][jj][1] + bv.y, 0.f));
                o.z = f2bf(fmaxf(acc[i][jj][2] + bv.z, 0.f));
                o.w = f2bf(fmaxf(acc[i][jj][3] + bv.w, 0.f));
                *(ushort4*)(dst + (long)p * C_ + f) = o;
            }
        }
    } else {
        float* dst = (float*)j.dst;
#pragma unroll
        for (int jj = 0; jj < 8; ++jj) {
            float s = 0.f;
#pragma unroll
            for (int i = 0; i < 4; ++i) {
                int f = fbase + i * 16;
                float4 bv = *(const float4*)(j.bias + f);
                float4 wv = *(const float4*)(j.wl + f);
                s += fmaxf(acc[i][jj][0] + bv.x, 0.f) * wv.x;
                s += fmaxf(acc[i][jj][1] + bv.y, 0.f) * wv.y;
                s += fmaxf(acc[i][jj][2] + bv.z, 0.f) * wv.z;
                s += fmaxf(acc[i][jj][3] + bv.w, 0.f) * wv.w;
            }
            s += __shfl_xor(s, 16, 64);
            s += __shfl_xor(s, 32, 64);
            if (l < 16) atomicAdd(dst + pbase + jj * 16, s);
        }
    }
}

// ---------------------------------------------------------------------------
extern "C" void kernel_launch(void* const* d_in, const int* in_sizes, int n_in,
                              void* d_out, int out_size, void* d_ws, size_t ws_size,
                              hipStream_t stream) {
    const float* H    = (const float*)d_in[0];
    const int*   Dgt  = (const int*)d_in[1];
    const float* Pgt  = (const float*)d_in[2];
    const float* Egt  = (const float*)d_in[3];
    const float* dp_w1 = (const float*)d_in[4];
    const float* dp_b1 = (const float*)d_in[5];
    const float* dp_w2 = (const float*)d_in[6];
    const float* dp_b2 = (const float*)d_in[7];
    const float* dp_wl = (const float*)d_in[8];
    const float* dp_bl = (const float*)d_in[9];
    const float* pp_w1 = (const float*)d_in[10];
    const float* pp_b1 = (const float*)d_in[11];
    const float* pp_w2 = (const float*)d_in[12];
    const float* pp_b2 = (const float*)d_in[13];
    const float* pp_wl = (const float*)d_in[14];
    const float* pp_bl = (const float*)d_in[15];
    const float* ep_w1 = (const float*)d_in[16];
    const float* ep_b1 = (const float*)d_in[17];
    const float* ep_w2 = (const float*)d_in[18];
    const float* ep_b2 = (const float*)d_in[19];
    const float* ep_wl = (const float*)d_in[20];
    const float* ep_bl = (const float*)d_in[21];
    const float* pitch_w  = (const float*)d_in[22];
    const float* pitch_b  = (const float*)d_in[23];
    const float* energy_w = (const float*)d_in[24];
    const float* energy_b = (const float*)d_in[25];

    float* out     = (float*)d_out;
    float* H_adapt = out;                       // 16*2048*512 = 16,777,216
    float* D_pred  = out + 16777216;            // 16*512 = 8192
    float* P_pred  = out + 16785408;            // 16*2048 = 32768
    float* E_pred  = out + 16818176;            // 16*2048 = 32768

    // ws_size is call-invariant, so this layout choice is graph-stable.
    const bool par = ws_size >= 94000000ull;    // parallel-ep plan needs ~89.1 MiB

    char* ws = (char*)d_ws;
    size_t off = 0;
    unsigned short* wpack = (unsigned short*)(ws + off); off += 6UL * 786432UL * 2UL;  // 9.4 MB
    unsigned short* Hbf   = (unsigned short*)(ws + off); off += 4194304UL * 2UL;       // 8 MB
    unsigned short* h1a   = (unsigned short*)(ws + off); off += 16777216UL * 2UL;      // 33.5 MB (pp)
    unsigned short* h1b   = par ? (unsigned short*)(ws + off) : h1a;                   // ep
    if (par) off += 16777216UL * 2UL;
    unsigned short* h1dp  = (unsigned short*)(ws + off); off += 4194304UL * 2UL;       // 8 MB
    unsigned short* zrow  = (unsigned short*)(ws + off); off += 512UL * 2UL;
    off = (off + 255) & ~(size_t)255;
    int* ridx_exp = (int*)(ws + off); off += (size_t)B_ * T_ * 4;

    hipLaunchKernelGGL(prep_kernel, dim3(10546), dim3(256), 0, stream,
                       dp_w1, dp_w2, pp_w1, pp_w2, ep_w1, ep_w2, wpack, H, Hbf, zrow,
                       Dgt, ridx_exp, D_pred, P_pred, E_pred, dp_bl, pp_bl, ep_bl);

    // nxshift = log2(position tiles at BN=512): pp 32768/512=64 -> 6; dp 8192/512=16 -> 4
    // grids: pp = 4(f) x 64 = 256 blocks; dp = 4 x 16 = 64 blocks
    ConvJob j_pp1 = { Hbf,  ridx_exp, 11,  9, wpack + 2UL * 786432, pp_b1, nullptr, h1a,    6 };
    ConvJob j_ep1 = { Hbf,  ridx_exp, 11,  9, wpack + 4UL * 786432, ep_b1, nullptr, h1b,    6 };
    ConvJob j_dp1 = { Hbf,  nullptr,   9,  9, wpack + 0UL * 786432, dp_b1, nullptr, h1dp,   4 };
    ConvJob j_pp2 = { h1a,  nullptr,  11, 11, wpack + 3UL * 786432, pp_b2, pp_wl,  P_pred, 6 };
    ConvJob j_ep2 = { h1b,  nullptr,  11, 11, wpack + 5UL * 786432, ep_b2, ep_wl,  E_pred, 6 };
    ConvJob j_dp2 = { h1dp, nullptr,   9,  9, wpack + 1UL * 786432, dp_b2, dp_wl,  D_pred, 4 };

    const unsigned lds_bytes = 114944;   // W 6x8192B + X 2x32896B

    if (par) {
        // conv1 all three (256+256+64=576) + half of adapt (512 blocks @512thr)
        hipLaunchKernelGGL(mega_kernel, dim3(576 + 512), dim3(512), lds_bytes, stream,
                           j_pp1, j_ep1, j_dp1, 256, 512, 576, 0, 0, zrow,
                           H, ridx_exp, Pgt, Egt, pitch_w, pitch_b, energy_w, energy_b, H_adapt);
        // conv2 + fused final linear + second half of adapt
        hipLaunchKernelGGL(mega_kernel, dim3(576 + 512), dim3(512), lds_bytes, stream,
                           j_pp2, j_ep2, j_dp2, 256, 512, 576, 1, 512, zrow,
                           H, ridx_exp, Pgt, Egt, pitch_w, pitch_b, energy_w, energy_b, H_adapt);
    } else {
        // serialized ep (h1b aliases h1a): pp+dp first (+all adapt), then ep
        hipLaunchKernelGGL(mega_kernel, dim3(320 + 1024), dim3(512), lds_bytes, stream,
                           j_pp1, j_dp1, j_dp1, 256, 320, 320, 0, 0, zrow,
                           H, ridx_exp, Pgt, Egt, pitch_w, pitch_b, energy_w, energy_b, H_adapt);
        hipLaunchKernelGGL(mega_kernel, dim3(320), dim3(512), lds_bytes, stream,
                           j_pp2, j_dp2, j_dp2, 256, 320, 320, 1, 0, zrow,
                           H, ridx_exp, Pgt, Egt, pitch_w, pitch_b, energy_w, energy_b, H_adapt);
        hipLaunchKernelGGL(mega_kernel, dim3(256), dim3(512), lds_bytes, stream,
                           j_ep1, j_ep1, j_ep1, 256, 256, 256, 0, 0, zrow,
                           H, ridx_exp, Pgt, Egt, pitch_w, pitch_b, energy_w, energy_b, H_adapt);
        hipLaunchKernelGGL(mega_kernel, dim3(256), dim3(512), lds_bytes, stream,
                           j_ep2, j_ep2, j_ep2, 256, 256, 256, 1, 0, zrow,
                           H, ridx_exp, Pgt, Egt, pitch_w, pitch_b, energy_w, energy_b, H_adapt);
    }
}

// Round 11
// 345.018 us; speedup vs baseline: 1.1480x; 1.1480x over previous
//
#include <hip/hip_runtime.h>

// VarianceAdaptor: B=16, S=512, C(D_MODEL)=F(FILTER)=512, K=3, T(MAX_FRAMES)=2048
#define B_ 16
#define S_ 512
#define C_ 512
#define T_ 2048

typedef __attribute__((ext_vector_type(8))) short short8;
typedef __attribute__((ext_vector_type(4))) float floatx4;

__device__ __forceinline__ unsigned short f2bf(float x) {
    union { float f; unsigned u; } c; c.f = x;
    unsigned r = (c.u + 0x7fffu + ((c.u >> 16) & 1u)) >> 16;
    return (unsigned short)r;
}

// async global->LDS, 16B per lane; lds dest = wave-uniform base + lane*16
__device__ __forceinline__ void gld_lds16(void* l, const void* g) {
    __builtin_amdgcn_global_load_lds(
        (const __attribute__((address_space(1))) void*)g,
        (__attribute__((address_space(3))) void*)l, 16, 0, 0);
}

// ---------------------------------------------------------------------------
// Prep v2: vectorized.  Weight pack via float4 reads + LDS transpose + ushort4
// writes (1536 blocks, was 6144 scalar); H cast 2 float4/thread (2048 blocks);
// zrow [3584..3585]; rowidx [3586..3601]; fill preds [3602..3889].
__global__ void prep_kernel(const float* __restrict__ w0, const float* __restrict__ w1,
                            const float* __restrict__ w2, const float* __restrict__ w3,
                            const float* __restrict__ w4, const float* __restrict__ w5,
                            unsigned short* __restrict__ wpack,
                            const float* __restrict__ H, unsigned short* __restrict__ Hbf,
                            unsigned short* __restrict__ zrow,
                            const int* __restrict__ Dgt, int* __restrict__ ridx,
                            float* __restrict__ Dp, float* __restrict__ Pp, float* __restrict__ Ep,
                            const float* __restrict__ dbl, const float* __restrict__ pbl,
                            const float* __restrict__ ebl) {
    __shared__ unsigned short wt[3][1024];
    __shared__ int cs[S_];
    __shared__ int ps[256];
    int blk = blockIdx.x;
    int tid = threadIdx.x;
    if (blk < 1536) {                      // weight pack: 6 x 256 blocks
        int which = blk >> 8;
        const float* w = which == 0 ? w0 : which == 1 ? w1 : which == 2 ? w2
                       : which == 3 ? w3 : which == 4 ? w4 : w5;
        int wblk = blk & 255;
        const float4* src = (const float4*)(w + wblk * 3072);
#pragma unroll
        for (int v = 0; v < 3; ++v) {
            float4 f = src[v * 256 + tid];
            int lf = (v * 256 + tid) * 4;          // local float idx, 0..3068
            wt[lf % 3][lf / 3]             = f2bf(f.x);
            wt[(lf + 1) % 3][(lf + 1) / 3] = f2bf(f.y);
            wt[(lf + 2) % 3][(lf + 2) / 3] = f2bf(f.z);
            wt[(lf + 3) % 3][(lf + 3) / 3] = f2bf(f.w);
        }
        __syncthreads();
        unsigned short* wp = wpack + (long)which * 786432 + wblk * 1024;
#pragma unroll
        for (int tap = 0; tap < 3; ++tap)
            *(ushort4*)(wp + tap * 262144 + tid * 4) = *(ushort4*)&wt[tap][tid * 4];
    } else if (blk < 3584) {               // H fp32 -> bf16: 2048 blocks x 2 float4
        long o = (long)(blk - 1536) * 512 + tid;
        float4 v0 = ((const float4*)H)[o];
        float4 v1 = ((const float4*)H)[o + 256];
        ushort4 a, b;
        a.x = f2bf(v0.x); a.y = f2bf(v0.y); a.z = f2bf(v0.z); a.w = f2bf(v0.w);
        b.x = f2bf(v1.x); b.y = f2bf(v1.y); b.z = f2bf(v1.z); b.w = f2bf(v1.w);
        ((ushort4*)Hbf)[o] = a;
        ((ushort4*)Hbf)[o + 256] = b;
    } else if (blk < 3586) {               // zrow: 2 blocks
        zrow[(blk - 3584) * 256 + tid] = 0;
    } else if (blk < 3602) {               // expand rowidx: 16 blocks (one/batch)
        int b = blk - 3586;
        int t2 = tid * 2;
        int d0 = Dgt[b * S_ + t2], d1 = Dgt[b * S_ + t2 + 1];
        int a0 = d0 < 0 ? 0 : d0, a1 = d1 < 0 ? 0 : d1;
        ps[tid] = a0 + a1;
        __syncthreads();
        for (int off = 1; off < 256; off <<= 1) {
            int v = (tid >= off) ? ps[tid - off] : 0;
            __syncthreads();
            ps[tid] += v;
            __syncthreads();
        }
        int incl = ps[tid];
        cs[t2] = incl - a1;
        cs[t2 + 1] = incl;
        __syncthreads();
        int total = cs[S_ - 1];
        int limit = total < T_ ? total : T_;
        for (int t = tid; t < T_; t += 256) {
            int lo = 0, hi = S_;
            while (lo < hi) { int mid = (lo + hi) >> 1; if (cs[mid] <= t) lo = mid + 1; else hi = mid; }
            if (lo > S_ - 1) lo = S_ - 1;
            ridx[b * T_ + t] = (t < limit) ? lo : -1;
        }
    } else {                               // fill preds: 288 blocks
        int i = (blk - 3602) * 256 + tid;
        if (i < 8192) Dp[i] = dbl[0];
        else if (i < 40960) Pp[i - 8192] = pbl[0];
        else Ep[i - 40960] = ebl[0];
    }
}

// ---------------------------------------------------------------------------
// 128(f) x 256(p) tile, 4 waves (2x2), wave = 64x128, acc[4][8].  BK=32,
// tap-minor counted-vmcnt pipeline (R7-verified: best measured, 344.6 us).
//   D[f, p] = sum_{tap, c} W[tap][f][c] * X[row(p + tap - 1)][c]
// K-tiles: c-block-major (cc=0..15), tap-minor.  X staged once per cc
// (parity cc&1, 5 instrs/wave incl. edge rows 256/257); W per kt (2 instrs,
// parity (cc+tap)&1).  Waits: tap0/tap1 vmcnt(0) (>=1 kt slack), tap2
// vmcnt(5): outstanding = 2 W(t2, 1kt old) + 5 X(just sent) = 7; drains the
// 2 W, keeps X flying (every wave issues all 5 X -- lanes 0,1 of each wave
// run issueXe -- so counts are wave-uniform; race-free).
// Swizzle (HW-verified, 0 conflicts): rows of 32 shorts (4 x 16B chunks);
// chunk c8 of row r holds global chunk c8 ^ ((r>>1)&3); linear LDS dest for
// global_load_lds, inverse-swizzled global source.
struct ConvJob {
    const unsigned short* X;    // bf16 rows [B << Bshift][C]
    const int* ridx;            // per (b,t) row-in-batch, or nullptr = identity
    int Lshift;                 // log2 positions per batch
    int Bshift;                 // log2 rows per batch of X
    const unsigned short* wp;   // [3][512][512] bf16
    const float* bias;
    const float* wl;
    void* dst;
    int nxshift;                // log2 of position tiles (BN=256)
};

template <int TAP>
__device__ __forceinline__ void compute_kt(
    floatx4 (&acc)[4][8],
    const unsigned short* Wb, const unsigned short* Xb,
    int wm, int wn, int q, int lr)
{
    // B (X) frags: row wn*128 + jj*16 + lr + TAP; stored chunk q^((row>>1)&3)
    short8 bfr[8];
    const int sX = ((lr + TAP) >> 1) & 3;
#pragma unroll
    for (int jj = 0; jj < 8; ++jj) {
        const int xr = wn * 128 + jj * 16 + lr + TAP;
        bfr[jj] = *(const short8*)(Xb + xr * 32 + ((q ^ sX) * 8));
    }
    const int sA = (lr >> 1) & 3;
#pragma unroll
    for (int i = 0; i < 4; ++i) {
        const int rA = wm * 64 + i * 16 + lr;
        short8 a = *(const short8*)(Wb + rA * 32 + ((q ^ sA) * 8));
#pragma unroll
        for (int jj = 0; jj < 8; ++jj)
            acc[i][jj] = __builtin_amdgcn_mfma_f32_16x16x32_bf16(a, bfr[jj], acc[i][jj], 0, 0, 0);
    }
}

// counted wait + publish barrier at K-tile start
#define VMWAIT(n) do { \
    asm volatile("s_waitcnt vmcnt(" #n ")" ::: "memory"); \
    __builtin_amdgcn_sched_barrier(0); \
    __builtin_amdgcn_s_barrier(); \
    __builtin_amdgcn_sched_barrier(0); \
} while (0)

__global__ __launch_bounds__(256, 2) void mega_kernel(
    ConvJob j0, ConvJob j1, ConvJob j2, int e0, int e1, int e2, int mode, int aoff,
    const unsigned short* __restrict__ zrow,
    const float* __restrict__ H, const int* __restrict__ aridx,
    const float* __restrict__ Pgt, const float* __restrict__ Egt,
    const float* __restrict__ pw, const float* __restrict__ pb,
    const float* __restrict__ ew, const float* __restrict__ eb,
    float* __restrict__ aout)
{
    extern __shared__ unsigned short lds[];   // 49408 B: W[2][4096] + X[2][8256] shorts
    const int bx = blockIdx.x;
    const int tid = threadIdx.x;

    if (bx >= e2) {
        // ---- adapt path: aoff selects which part of the 2048-block range ----
        int ab = bx - e2 + aoff;
#pragma unroll
        for (int it = 0; it < 8; ++it) {
            int i = ab * 256 + tid + it * 524288;
            int f4 = i & 127;
            int p  = i >> 7;
            int b  = p >> 11;
            int r  = aridx[p];
            float pg = Pgt[p], eg = Egt[p];
            int f = f4 << 2;
            float4 pwv = *(const float4*)(pw + f);
            float4 pbv = *(const float4*)(pb + f);
            float4 ewv = *(const float4*)(ew + f);
            float4 ebv = *(const float4*)(eb + f);
            float4 h = make_float4(0.f, 0.f, 0.f, 0.f);
            if (r >= 0) h = *(const float4*)(H + ((long)b * S_ + r) * C_ + f);
            float4 o;
            o.x = h.x + pg * pwv.x + pbv.x + eg * ewv.x + ebv.x;
            o.y = h.y + pg * pwv.y + pbv.y + eg * ewv.y + ebv.y;
            o.z = h.z + pg * pwv.z + pbv.z + eg * ewv.z + ebv.z;
            o.w = h.w + pg * pwv.w + pbv.w + eg * ewv.w + ebv.w;
            *(float4*)(aout + (long)p * C_ + f) = o;
        }
        return;
    }

    ConvJob j;
    int local;
    if (bx < e0)      { j = j0; local = bx; }
    else if (bx < e1) { j = j1; local = bx - e0; }
    else              { j = j2; local = bx - e1; }
    const int m0 = (local >> j.nxshift) * 128;              // f tile (BM=128)
    const int n0 = (local & ((1 << j.nxshift) - 1)) * 256;  // p tile (BN=256)
    const int L = 1 << j.Lshift;
    const int b = n0 >> j.Lshift;
    const int t0 = n0 & (L - 1);

    unsigned short* WtS = lds;            // [2][4096]  (128 rows x 32) x 2
    unsigned short* XtS = lds + 8192;     // [2][8256]  (258 rows x 32) x 2
    char* WtB = (char*)WtS;
    char* XtB = (char*)XtS;

    const int w = tid >> 6, l = tid & 63;
    const int q = l >> 4, lr = l & 15;
    const int wm = w & 1, wn = w >> 1;

    floatx4 acc[4][8];
#pragma unroll
    for (int i = 0; i < 4; ++i)
#pragma unroll
        for (int jj = 0; jj < 8; ++jj) acc[i][jj] = (floatx4){0.f, 0.f, 0.f, 0.f};

    // ---- staging sources (16B chunks; inverse-swizzled source column) ----
    // issue qq stages chunk ch = qq*256 + tid: row = qq*64 + (tid>>2), c8 = tid&3;
    // source col-chunk = c8 ^ ((row>>1)&3) = (tid&3) ^ ((tid>>3)&3).
    const int sw = (((tid & 3) ^ ((tid >> 3) & 3))) * 8;
    auto xrowp = [&](int r) -> const unsigned short* {
        int t = t0 - 1 + r;
        if (t < 0 || t >= L) return zrow;
        int rr = j.ridx ? j.ridx[(b << j.Lshift) + t] : t;
        if (rr < 0) return zrow;
        return j.X + ((long)(b << j.Bshift) + rr) * C_;
    };
    const unsigned short* wsrc[2];
    const unsigned short* xsrc[4];
#pragma unroll
    for (int qq = 0; qq < 2; ++qq)
        wsrc[qq] = j.wp + (long)(m0 + qq * 64 + (tid >> 2)) * C_ + sw;
#pragma unroll
    for (int qq = 0; qq < 4; ++qq)
        xsrc[qq] = xrowp(qq * 64 + (tid >> 2)) + sw;
    // extra X rows 256,257: chunks ch_e = w*2 + (l&1); (row_e>>1)&3 == 0
    const int ch_e = w * 2 + (l & 1);
    const unsigned short* xsrcE = xrowp(256 + (ch_e >> 2)) + (ch_e & 3) * 8;

    auto issueW = [&](int buf, int koff) {             // 2 instrs, 8 KB
        gld_lds16(WtB + buf * 8192 + 0 * 4096 + w * 1024, wsrc[0] + koff);
        gld_lds16(WtB + buf * 8192 + 1 * 4096 + w * 1024, wsrc[1] + koff);
    };
    auto issueX = [&](int buf, int xoff) {             // 5 instrs, 16.5 KB
        gld_lds16(XtB + buf * 16512 + 0 * 4096 + w * 1024, xsrc[0] + xoff);
        gld_lds16(XtB + buf * 16512 + 1 * 4096 + w * 1024, xsrc[1] + xoff);
        gld_lds16(XtB + buf * 16512 + 2 * 4096 + w * 1024, xsrc[2] + xoff);
        gld_lds16(XtB + buf * 16512 + 3 * 4096 + w * 1024, xsrc[3] + xoff);
        if (l < 2)
            gld_lds16(XtB + buf * 16512 + 16384 + w * 32, xsrcE + xoff);
    };

    // ---- prologue: X(cc=0) [5 ops] + W(cc0,tap0) [2 ops] ----
    issueX(0, 0);
    issueW(0, 0);

    // ---- main loop.  W parity of kt (cc,tap) = (cc+tap)&1; X parity = cc&1.
    // Waits at kt start (outstanding per wave -> count):
    //  tap0: X(cc)[5] + W(t0)[2], all >= 1 kt old      -> vmcnt(0)
    //  tap1: W(t1)[2], 1 kt old                        -> vmcnt(0)
    //  tap2: W(t2)[2, 1kt old] + X(cc+1)[5, just sent] -> vmcnt(5) keep X flying
#pragma unroll 1
    for (int cc = 0; cc < 16; ++cc) {
        const int xb = cc & 1;
        const unsigned short* Xb = XtS + xb * 8256;
        const unsigned short* W0 = WtS + xb * 4096;          // parity cc&1 (tap0, tap2)
        const unsigned short* W1 = WtS + (xb ^ 1) * 4096;    // parity (cc+1)&1 (tap1)
        const int kW1 = 262144 + cc * 32;   // W col-off tap1
        const int kW2 = 524288 + cc * 32;   // W col-off tap2
        const int kW0n = cc * 32 + 32;      // W col-off tap0 of cc+1
        const int xoffn = cc * 32 + 32;     // X cols of cc+1
        const bool more = (cc < 15);

        // tap0: read W0; stage W(t1) -> parity xb^1
        VMWAIT(0);
        issueW(xb ^ 1, kW1);
        compute_kt<0>(acc, W0, Xb, wm, wn, q, lr);

        // tap1: read W1; stage W(t2) -> parity xb; stage X(cc+1) -> parity xb^1
        VMWAIT(0);
        issueW(xb, kW2);
        if (more) issueX(xb ^ 1, xoffn);
        compute_kt<1>(acc, W1, Xb, wm, wn, q, lr);

        // tap2: read W0 (= W(t2)); stage W(t0,cc+1) -> parity xb^1
        if (more) { VMWAIT(5); } else { VMWAIT(0); }
        if (more) issueW(xb ^ 1, kW0n);
        compute_kt<2>(acc, W0, Xb, wm, wn, q, lr);
    }

    // ---- epilogue: D col = lane&15 = p, row = q*4 + reg = f ----
    const int fbase = m0 + wm * 64 + q * 4;
    const int pbase = n0 + wn * 128 + lr;
    if (mode == 0) {
        unsigned short* dst = (unsigned short*)j.dst;
#pragma unroll
        for (int i = 0; i < 4; ++i) {
            int f = fbase + i * 16;
            float4 bv = *(const float4*)(j.bias + f);
#pragma unroll
            for (int jj = 0; jj < 8; ++jj) {
                int p = pbase + jj * 16;
                ushort4 o;
                o.x = f2bf(fmaxf(acc[i][jj][0] + bv.x, 0.f));
                o.y = f2bf(fmaxf(acc[i][jj][1] + bv.y, 0.f));
                o.z = f2bf(fmaxf(acc[i][jj][2] + bv.z, 0.f));
                o.w = f2bf(fmaxf(acc[i][jj][3] + bv.w, 0.f));
                *(ushort4*)(dst + (long)p * C_ + f) = o;
            }
        }
    } else {
        float* dst = (float*)j.dst;
#pragma unroll
        for (int jj = 0; jj < 8; ++jj) {
            float s = 0.f;
#pragma unroll
            for (int i = 0; i < 4; ++i) {
                int f = fbase + i * 16;
                float4 bv = *(const float4*)(j.bias + f);
                float4 wv = *(const float4*)(j.wl + f);
                s += fmaxf(acc[i][jj][0] + bv.x, 0.f) * wv.x;
                s += fmaxf(acc[i][jj][1] + bv.y, 0.f) * wv.y;
                s += fmaxf(acc[i][jj][2] + bv.z, 0.f) * wv.z;
                s += fmaxf(acc[i][jj][3] + bv.w, 0.f) * wv.w;
            }
            s += __shfl_xor(s, 16, 64);
            s += __shfl_xor(s, 32, 64);
            if (l < 16) atomicAdd(dst + pbase + jj * 16, s);
        }
    }
}

// ---------------------------------------------------------------------------
extern "C" void kernel_launch(void* const* d_in, const int* in_sizes, int n_in,
                              void* d_out, int out_size, void* d_ws, size_t ws_size,
                              hipStream_t stream) {
    const float* H    = (const float*)d_in[0];
    const int*   Dgt  = (const int*)d_in[1];
    const float* Pgt  = (const float*)d_in[2];
    const float* Egt  = (const float*)d_in[3];
    const float* dp_w1 = (const float*)d_in[4];
    const float* dp_b1 = (const float*)d_in[5];
    const float* dp_w2 = (const float*)d_in[6];
    const float* dp_b2 = (const float*)d_in[7];
    const float* dp_wl = (const float*)d_in[8];
    const float* dp_bl = (const float*)d_in[9];
    const float* pp_w1 = (const float*)d_in[10];
    const float* pp_b1 = (const float*)d_in[11];
    const float* pp_w2 = (const float*)d_in[12];
    const float* pp_b2 = (const float*)d_in[13];
    const float* pp_wl = (const float*)d_in[14];
    const float* pp_bl = (const float*)d_in[15];
    const float* ep_w1 = (const float*)d_in[16];
    const float* ep_b1 = (const float*)d_in[17];
    const float* ep_w2 = (const float*)d_in[18];
    const float* ep_b2 = (const float*)d_in[19];
    const float* ep_wl = (const float*)d_in[20];
    const float* ep_bl = (const float*)d_in[21];
    const float* pitch_w  = (const float*)d_in[22];
    const float* pitch_b  = (const float*)d_in[23];
    const float* energy_w = (const float*)d_in[24];
    const float* energy_b = (const float*)d_in[25];

    float* out     = (float*)d_out;
    float* H_adapt = out;                       // 16*2048*512 = 16,777,216
    float* D_pred  = out + 16777216;            // 16*512 = 8192
    float* P_pred  = out + 16785408;            // 16*2048 = 32768
    float* E_pred  = out + 16818176;            // 16*2048 = 32768

    // ws_size is call-invariant, so this layout choice is graph-stable.
    const bool par = ws_size >= 94000000ull;    // parallel-ep plan needs ~89.1 MiB

    char* ws = (char*)d_ws;
    size_t off = 0;
    unsigned short* wpack = (unsigned short*)(ws + off); off += 6UL * 786432UL * 2UL;  // 9.4 MB
    unsigned short* Hbf   = (unsigned short*)(ws + off); off += 4194304UL * 2UL;       // 8 MB
    unsigned short* h1a   = (unsigned short*)(ws + off); off += 16777216UL * 2UL;      // 33.5 MB (pp)
    unsigned short* h1b   = par ? (unsigned short*)(ws + off) : h1a;                   // ep
    if (par) off += 16777216UL * 2UL;
    unsigned short* h1dp  = (unsigned short*)(ws + off); off += 4194304UL * 2UL;       // 8 MB
    unsigned short* zrow  = (unsigned short*)(ws + off); off += 512UL * 2UL;
    off = (off + 255) & ~(size_t)255;
    int* ridx_exp = (int*)(ws + off); off += (size_t)B_ * T_ * 4;

    hipLaunchKernelGGL(prep_kernel, dim3(3890), dim3(256), 0, stream,
                       dp_w1, dp_w2, pp_w1, pp_w2, ep_w1, ep_w2, wpack, H, Hbf, zrow,
                       Dgt, ridx_exp, D_pred, P_pred, E_pred, dp_bl, pp_bl, ep_bl);

    // nxshift = log2(position tiles at BN=256): pp 32768/256=128 -> 7; dp 8192/256=32 -> 5
    // grids: pp = 4(f) x 128 = 512 blocks; dp = 4 x 32 = 128 blocks
    ConvJob j_pp1 = { Hbf,  ridx_exp, 11,  9, wpack + 2UL * 786432, pp_b1, nullptr, h1a,    7 };
    ConvJob j_ep1 = { Hbf,  ridx_exp, 11,  9, wpack + 4UL * 786432, ep_b1, nullptr, h1b,    7 };
    ConvJob j_dp1 = { Hbf,  nullptr,   9,  9, wpack + 0UL * 786432, dp_b1, nullptr, h1dp,   5 };
    ConvJob j_pp2 = { h1a,  nullptr,  11, 11, wpack + 3UL * 786432, pp_b2, pp_wl,  P_pred, 7 };
    ConvJob j_ep2 = { h1b,  nullptr,  11, 11, wpack + 5UL * 786432, ep_b2, ep_wl,  E_pred, 7 };
    ConvJob j_dp2 = { h1dp, nullptr,   9,  9, wpack + 1UL * 786432, dp_b2, dp_wl,  D_pred, 5 };

    const unsigned lds_bytes = 49408;   // W 2x8192B + X 2x16512B

    if (par) {
        // conv1 all three (512+512+128=1152) + half of adapt (1024)
        hipLaunchKernelGGL(mega_kernel, dim3(1152 + 1024), dim3(256), lds_bytes, stream,
                           j_pp1, j_ep1, j_dp1, 512, 1024, 1152, 0, 0, zrow,
                           H, ridx_exp, Pgt, Egt, pitch_w, pitch_b, energy_w, energy_b, H_adapt);
        // conv2 + fused final linear + second half of adapt
        hipLaunchKernelGGL(mega_kernel, dim3(1152 + 1024), dim3(256), lds_bytes, stream,
                           j_pp2, j_ep2, j_dp2, 512, 1024, 1152, 1, 1024, zrow,
                           H, ridx_exp, Pgt, Egt, pitch_w, pitch_b, energy_w, energy_b, H_adapt);
    } else {
        // serialized ep (h1b aliases h1a): pp+dp first (+all adapt), then ep
        hipLaunchKernelGGL(mega_kernel, dim3(640 + 2048), dim3(256), lds_bytes, stream,
                           j_pp1, j_dp1, j_dp1, 512, 640, 640, 0, 0, zrow,
                           H, ridx_exp, Pgt, Egt, pitch_w, pitch_b, energy_w, energy_b, H_adapt);
        hipLaunchKernelGGL(mega_kernel, dim3(640), dim3(256), lds_bytes, stream,
                           j_pp2, j_dp2, j_dp2, 512, 640, 640, 1, 0, zrow,
                           H, ridx_exp, Pgt, Egt, pitch_w, pitch_b, energy_w, energy_b, H_adapt);
        hipLaunchKernelGGL(mega_kernel, dim3(512), dim3(256), lds_bytes, stream,
                           j_ep1, j_ep1, j_ep1, 512, 512, 512, 0, 0, zrow,
                           H, ridx_exp, Pgt, Egt, pitch_w, pitch_b, energy_w, energy_b, H_adapt);
        hipLaunchKernelGGL(mega_kernel, dim3(512), dim3(256), lds_bytes, stream,
                           j_ep2, j_ep2, j_ep2, 512, 512, 512, 1, 0, zrow,
                           H, ridx_exp, Pgt, Egt, pitch_w, pitch_b, energy_w, energy_b, H_adapt);
    }
}